// Round 3
// baseline (328.444 us; speedup 1.0000x reference)
//
#include <hip/hip_runtime.h>
#include <stdint.h>

// Fused attention: q/k/v projections + softmax(QK^T/32 + mask) @ V
// B=4, S=2048, E=1024.
// GEMM: m201-style 8-phase 256x256 tile, BK=64, 8 waves (2Mx4N),
// per-wave 128x64 out, dbuf LDS 128KB, half-tile-staggered
// global_load_lds staging with counted vmcnt(4) gates, 2-bit XOR swizzle,
// setprio MFMA clusters, bijective XCD swizzle, multi-job grid.
//
// ws layout (MB offsets): 0 qb / 16 kb / 32 vT / 48 Sb(32MB) / 80 xq /
// 96 xk / 112 xv / 128 Wqb / 130 Wkb / 132 Wvb   (total 134MB)

typedef __attribute__((ext_vector_type(8))) short s8v;
typedef __attribute__((ext_vector_type(4))) float f32x4;

__device__ __forceinline__ unsigned short f2b(float f) {
  union { float f; unsigned u; } c; c.f = f;
  unsigned r = c.u + 0x7fffu + ((c.u >> 16) & 1u);
  return (unsigned short)(r >> 16);
}
__device__ __forceinline__ float b2f(unsigned short s) {
  union { float f; unsigned u; } c; c.u = ((unsigned)s) << 16; return c.f;
}

__device__ __forceinline__ void gload_lds16(const void* gsrc, void* ldst) {
  __builtin_amdgcn_global_load_lds(
      (__attribute__((address_space(1))) unsigned int*)(uintptr_t)gsrc,
      (__attribute__((address_space(3))) unsigned int*)(unsigned)(uintptr_t)ldst,
      16, 0, 0);
}

template <int N> __device__ __forceinline__ void waitvm() {
  if constexpr (N == 4)      asm volatile("s_waitcnt vmcnt(4)" ::: "memory");
  else if constexpr (N == 2) asm volatile("s_waitcnt vmcnt(2)" ::: "memory");
  else                       asm volatile("s_waitcnt vmcnt(0)" ::: "memory");
}
#define BAR() do { __builtin_amdgcn_sched_barrier(0); \
  asm volatile("s_barrier" ::: "memory"); \
  __builtin_amdgcn_sched_barrier(0); } while (0)

struct Job {
  const unsigned short* A; const unsigned short* B; void* C;
  const float* bias; const float* mask;
  long sAb, sBb, sCb, sMb;
  int lda, ldb, ldc, ldM;
  int K, tilesN, tilesMN;
  float scale; int flags;   // bit0: out bf16; bits1-2: bias 0/1(col)/2(row); bit3: mask
};

// 8-phase 256x256 GEMM, NT layout: C[m][n] = scale*sum_k A[m][k]B[n][k] (+bias/mask)
__global__ __launch_bounds__(512, 2) void gemm8p(Job j0, Job j1, Job j2,
                                                 int b0, int b1) {
  __shared__ __align__(16) char lds[131072];   // A: [buf][256][128B] @0; B @65536

  const int nwg = gridDim.x;
  int hw = blockIdx.x;
  int g = (hw & 7) * (nwg >> 3) + (hw >> 3);   // XCD-contiguous tiles
  const Job J = (g < b0) ? j0 : (g < b1) ? j1 : j2;
  g -= (g < b0) ? 0 : (g < b1) ? b0 : b1;

  const int batch = g / J.tilesMN;
  const int tt = g - batch * J.tilesMN;
  const int tm = tt / J.tilesN, tn = tt - tm * J.tilesN;
  const int brow = tm << 8, bcol = tn << 8;

  const int tid = threadIdx.x;
  const int lane = tid & 63, w = tid >> 6;     // 8 waves, 2M x 4N
  const int wm = w >> 2, wn = w & 3;
  const int fr = lane & 15, fq = lane >> 4;

  const unsigned short* Ab = J.A + (long)batch * J.sAb;
  const unsigned short* Bb = J.B + (long)batch * J.sBb;

  // staging sources (per-lane, tile-invariant; +kt*64 elems per K-tile) and
  // wave-uniform LDS dests. Physical LDS is linear; source is inverse-swizzled.
  const unsigned short* srcA[2][2]; const unsigned short* srcB[2][2];
  int dstO[2][2];
#pragma unroll
  for (int h = 0; h < 2; h++)
#pragma unroll
    for (int i = 0; i < 2; i++) {
      const int P = h * 16384 + w * 2048 + i * 1024 + lane * 16;
      const int L = P ^ (((P >> 9) & 3) << 5);
      const int row = L >> 7, colb = L & 127;
      srcA[h][i] = Ab + (long)(brow + row) * J.lda + (colb >> 1);
      srcB[h][i] = Bb + (long)(bcol + row) * J.ldb + (colb >> 1);
      dstO[h][i] = h * 16384 + w * 2048 + i * 1024;
    }

  // ds_read offsets (swizzled; ks toggles bit6 via XOR)
  int offA[8], offB[4];
#pragma unroll
  for (int mi = 0; mi < 8; mi++) {
    const int rowL = (mi < 4 ? wm * 64 + mi * 16 : 128 + wm * 64 + (mi - 4) * 16) + fr;
    offA[mi] = (rowL * 128 + fq * 16) ^ (((rowL >> 2) & 3) << 5);
  }
#pragma unroll
  for (int ni = 0; ni < 4; ni++) {
    const int rowL = (ni < 2 ? wn * 32 + ni * 16 : 128 + wn * 32 + (ni - 2) * 16) + fr;
    offB[ni] = (rowL * 128 + fq * 16) ^ (((rowL >> 2) & 3) << 5);
  }

  f32x4 acc[8][4];
#pragma unroll
  for (int mi = 0; mi < 8; mi++)
#pragma unroll
    for (int ni = 0; ni < 4; ni++) acc[mi][ni] = (f32x4){0.f, 0.f, 0.f, 0.f};

  const int NT = J.K >> 6;

#define STG_A(h, kt, d1) { \
  gload_lds16(srcA[h][0] + (long)(kt) * 64, lds + (d1) * 32768 + dstO[h][0]); \
  gload_lds16(srcA[h][1] + (long)(kt) * 64, lds + (d1) * 32768 + dstO[h][1]); }
#define STG_B(h, kt, d1) { \
  gload_lds16(srcB[h][0] + (long)(kt) * 64, lds + 65536 + (d1) * 32768 + dstO[h][0]); \
  gload_lds16(srcB[h][1] + (long)(kt) * 64, lds + 65536 + (d1) * 32768 + dstO[h][1]); }

  // prologue: K-tile 0 into buf 0 (order A0,B0,B1,A1 = steady order)
  STG_A(0, 0, 0); STG_B(0, 0, 0); STG_B(1, 0, 0); STG_A(1, 0, 0);
  waitvm<4>();
  BAR();

  s8v a[4][2], bb0[2][2], bb1[2][2];
  for (int t = 0; t < NT; ++t) {
    const int d = t & 1, d1 = d ^ 1;
    const char* rdA = lds + d * 32768;
    const char* rdB = lds + 65536 + d * 32768;
    const bool st = (t + 1 < NT);

    // ---- phase 0: read A-m0 + B-n0; stage A-h0(t+1); MFMA m0n0
#pragma unroll
    for (int mi = 0; mi < 4; mi++) {
      a[mi][0] = *(const s8v*)(rdA + offA[mi]);
      a[mi][1] = *(const s8v*)(rdA + (offA[mi] ^ 64));
    }
#pragma unroll
    for (int ni = 0; ni < 2; ni++) {
      bb0[ni][0] = *(const s8v*)(rdB + offB[ni]);
      bb0[ni][1] = *(const s8v*)(rdB + (offB[ni] ^ 64));
    }
    if (st) STG_A(0, t + 1, d1);
    BAR();
    __builtin_amdgcn_s_setprio(1);
#pragma unroll
    for (int mi = 0; mi < 4; mi++)
#pragma unroll
      for (int ni = 0; ni < 2; ni++)
#pragma unroll
        for (int ks = 0; ks < 2; ks++)
          acc[mi][ni] = __builtin_amdgcn_mfma_f32_16x16x32_bf16(
              a[mi][ks], bb0[ni][ks], acc[mi][ni], 0, 0, 0);
    __builtin_amdgcn_s_setprio(0);
    if (st) waitvm<4>(); else waitvm<2>();   // B-h1(t) landed
    BAR();

    // ---- phase 1: read B-n1; stage B-h0(t+1); MFMA m0n1
#pragma unroll
    for (int ni = 0; ni < 2; ni++) {
      bb1[ni][0] = *(const s8v*)(rdB + offB[2 + ni]);
      bb1[ni][1] = *(const s8v*)(rdB + (offB[2 + ni] ^ 64));
    }
    if (st) STG_B(0, t + 1, d1);
    BAR();
    __builtin_amdgcn_s_setprio(1);
#pragma unroll
    for (int mi = 0; mi < 4; mi++)
#pragma unroll
      for (int ni = 0; ni < 2; ni++)
#pragma unroll
        for (int ks = 0; ks < 2; ks++)
          acc[mi][2 + ni] = __builtin_amdgcn_mfma_f32_16x16x32_bf16(
              a[mi][ks], bb1[ni][ks], acc[mi][2 + ni], 0, 0, 0);
    __builtin_amdgcn_s_setprio(0);
    if (st) waitvm<4>(); else waitvm<0>();   // A-h1(t) landed
    BAR();

    // ---- phase 2: read A-m1; stage B-h1(t+1); MFMA m1n1
#pragma unroll
    for (int mi = 0; mi < 4; mi++) {
      a[mi][0] = *(const s8v*)(rdA + offA[4 + mi]);
      a[mi][1] = *(const s8v*)(rdA + (offA[4 + mi] ^ 64));
    }
    if (st) STG_B(1, t + 1, d1);
    BAR();
    __builtin_amdgcn_s_setprio(1);
#pragma unroll
    for (int mi = 0; mi < 4; mi++)
#pragma unroll
      for (int ni = 0; ni < 2; ni++)
#pragma unroll
        for (int ks = 0; ks < 2; ks++)
          acc[4 + mi][2 + ni] = __builtin_amdgcn_mfma_f32_16x16x32_bf16(
              a[mi][ks], bb1[ni][ks], acc[4 + mi][2 + ni], 0, 0, 0);
    __builtin_amdgcn_s_setprio(0);
    BAR();

    // ---- phase 3: stage A-h1(t+1); MFMA m1n0 (A-m1, B-n0 held in regs)
    if (st) STG_A(1, t + 1, d1);
    BAR();
    __builtin_amdgcn_s_setprio(1);
#pragma unroll
    for (int mi = 0; mi < 4; mi++)
#pragma unroll
      for (int ni = 0; ni < 2; ni++)
#pragma unroll
        for (int ks = 0; ks < 2; ks++)
          acc[4 + mi][ni] = __builtin_amdgcn_mfma_f32_16x16x32_bf16(
              a[mi][ks], bb0[ni][ks], acc[4 + mi][ni], 0, 0, 0);
    __builtin_amdgcn_s_setprio(0);
    if (st) waitvm<4>();                     // A-h0,B-h0(t+1) landed
    BAR();
  }

  // epilogue: C/D frag layout col=lane&15, row=(lane>>4)*4+r  [m89]
  const int obf = J.flags & 1, bmode = (J.flags >> 1) & 3, hasM = (J.flags >> 3) & 1;
  unsigned short* Cb = (unsigned short*)J.C;
  float* Cf = (float*)J.C;
  const long cB = (long)batch * J.sCb;
  const float* maskB = J.mask + (long)batch * J.sMb;
#pragma unroll
  for (int mi = 0; mi < 8; mi++) {
    const int rloc = (mi < 4 ? wm * 64 + mi * 16 : 128 + wm * 64 + (mi - 4) * 16) + fq * 4;
#pragma unroll
    for (int ni = 0; ni < 4; ni++) {
      const int col = bcol + (ni < 2 ? wn * 32 + ni * 16 : 128 + wn * 32 + (ni - 2) * 16) + fr;
#pragma unroll
      for (int r = 0; r < 4; r++) {
        const int row = brow + rloc + r;
        float v = acc[mi][ni][r] * J.scale;
        if (bmode == 1) v += J.bias[col];
        if (bmode == 2) v += J.bias[row];
        if (hasM) v += maskB[(long)row * J.ldM + col];
        if (obf) Cb[cB + (long)row * J.ldc + col] = f2b(v);
        else     Cf[cB + (long)row * J.ldc + col] = v;
      }
    }
  }
#undef STG_A
#undef STG_B
}

// f32->bf16 for 6 regions in one launch. regions 0-2: n8=1048576, 768 blocks
// each; regions 3-5: n8=131072, 128 blocks each. grid = 2688.
__global__ __launch_bounds__(256) void cvt6(
    const float* s0, unsigned short* d0, const float* s1, unsigned short* d1,
    const float* s2, unsigned short* d2, const float* s3, unsigned short* d3,
    const float* s4, unsigned short* d4, const float* s5, unsigned short* d5) {
  int bid = blockIdx.x;
  const float* src; unsigned short* dst; long n8; int lb, nb;
  if (bid < 2304) {
    int r = bid / 768; lb = bid - r * 768; nb = 768; n8 = 1048576;
    src = r == 0 ? s0 : r == 1 ? s1 : s2;
    dst = r == 0 ? d0 : r == 1 ? d1 : d2;
  } else {
    int r = (bid - 2304) / 128; lb = (bid - 2304) - r * 128; nb = 128; n8 = 131072;
    src = r == 0 ? s3 : r == 1 ? s4 : s5;
    dst = r == 0 ? d3 : r == 1 ? d4 : d5;
  }
  const long stride = (long)nb * 256;
  for (long i = (long)lb * 256 + threadIdx.x; i < n8; i += stride) {
    const float* p = src + i * 8;
    f32x4 va = *(const f32x4*)p;
    f32x4 vb = *(const f32x4*)(p + 4);
    s8v o;
    o[0] = (short)f2b(va[0]); o[1] = (short)f2b(va[1]);
    o[2] = (short)f2b(va[2]); o[3] = (short)f2b(va[3]);
    o[4] = (short)f2b(vb[0]); o[5] = (short)f2b(vb[1]);
    o[6] = (short)f2b(vb[2]); o[7] = (short)f2b(vb[3]);
    *(s8v*)(dst + i * 8) = o;
  }
}

// in-place row softmax over 2048 bf16 entries; one block (4 waves) per row
__global__ __launch_bounds__(256) void softmax_inplace(unsigned short* __restrict__ S) {
  const long row = blockIdx.x;
  unsigned short* rp = S + row * 2048;
  const int tid = threadIdx.x, lane = tid & 63, wid = tid >> 6;

  s8v vb = *(const s8v*)&rp[tid * 8];
  float x[8];
#pragma unroll
  for (int j = 0; j < 8; j++) x[j] = b2f((unsigned short)vb[j]);

  float m = x[0];
#pragma unroll
  for (int j = 1; j < 8; j++) m = fmaxf(m, x[j]);
#pragma unroll
  for (int off = 32; off > 0; off >>= 1) m = fmaxf(m, __shfl_xor(m, off, 64));

  __shared__ float red[4];
  if (lane == 0) red[wid] = m;
  __syncthreads();
  m = fmaxf(fmaxf(red[0], red[1]), fmaxf(red[2], red[3]));
  __syncthreads();

  float s = 0.f;
#pragma unroll
  for (int j = 0; j < 8; j++) { x[j] = __expf(x[j] - m); s += x[j]; }
#pragma unroll
  for (int off = 32; off > 0; off >>= 1) s += __shfl_xor(s, off, 64);
  if (lane == 0) red[wid] = s;
  __syncthreads();
  s = red[0] + red[1] + red[2] + red[3];
  const float inv = 1.0f / s;

  s8v ob;
#pragma unroll
  for (int j = 0; j < 8; j++) ob[j] = (short)f2b(x[j] * inv);
  *(s8v*)&rp[tid * 8] = ob;
}

extern "C" void kernel_launch(void* const* d_in, const int* in_sizes, int n_in,
                              void* d_out, int out_size, void* d_ws, size_t ws_size,
                              hipStream_t stream) {
  const float* q    = (const float*)d_in[0];
  const float* k    = (const float*)d_in[1];
  const float* v    = (const float*)d_in[2];
  const float* mask = (const float*)d_in[3];
  const float* Wq   = (const float*)d_in[4];
  const float* bq   = (const float*)d_in[5];
  const float* Wk   = (const float*)d_in[6];
  const float* bk   = (const float*)d_in[7];
  const float* Wv   = (const float*)d_in[8];
  const float* bv   = (const float*)d_in[9];
  float* out = (float*)d_out;

  const size_t MB = 1ull << 20;
  if (ws_size < 134 * MB) return;
  char* ws = (char*)d_ws;
  unsigned short* qb  = (unsigned short*)(ws + 0 * MB);
  unsigned short* kb  = (unsigned short*)(ws + 16 * MB);
  unsigned short* vT  = (unsigned short*)(ws + 32 * MB);
  unsigned short* Sb  = (unsigned short*)(ws + 48 * MB);
  unsigned short* xq  = (unsigned short*)(ws + 80 * MB);
  unsigned short* xk  = (unsigned short*)(ws + 96 * MB);
  unsigned short* xv  = (unsigned short*)(ws + 112 * MB);
  unsigned short* Wqb = (unsigned short*)(ws + 128 * MB);
  unsigned short* Wkb = (unsigned short*)(ws + 130 * MB);
  unsigned short* Wvb = (unsigned short*)(ws + 132 * MB);

  cvt6<<<2688, 256, 0, stream>>>(q, xq, k, xk, v, xv, Wq, Wqb, Wk, Wkb, Wv, Wvb);

  Job jq = { xq, Wqb, (void*)qb, bq, nullptr, 0, 0, 0, 0,
             1024, 1024, 1024, 0, 1024, 4, 128, 1.0f, 1 | (1 << 1) };
  Job jk = { xk, Wkb, (void*)kb, bk, nullptr, 0, 0, 0, 0,
             1024, 1024, 1024, 0, 1024, 4, 128, 1.0f, 1 | (1 << 1) };
  Job jv = { Wvb, xv, (void*)vT, bv, nullptr, 0, 2048L * 1024, 1024L * 2048, 0,
             1024, 1024, 2048, 0, 1024, 8, 32, 1.0f, 1 | (2 << 1) };
  gemm8p<<<384, 512, 0, stream>>>(jq, jk, jv, 128, 256);

  Job js = { qb, kb, (void*)Sb, nullptr, mask,
             2048L * 1024, 2048L * 1024, 2048L * 2048, 2048L * 2048,
             1024, 1024, 2048, 2048, 1024, 8, 64, 0.03125f, 1 | (1 << 3) };
  gemm8p<<<256, 512, 0, stream>>>(js, js, js, 256, 256);

  softmax_inplace<<<8192, 256, 0, stream>>>(Sb);

  Job jp = { Sb, vT, (void*)out, nullptr, nullptr,
             2048L * 2048, 1024L * 2048, 2048L * 1024, 0,
             2048, 2048, 1024, 0, 2048, 4, 32, 1.0f, 0 };
  gemm8p<<<128, 512, 0, stream>>>(jp, jp, jp, 128, 128);
}

// Round 4
// 315.181 us; speedup vs baseline: 1.0421x; 1.0421x over previous
//
#include <hip/hip_runtime.h>
#include <stdint.h>

// Fused attention: q/k/v projections + softmax(QK^T/32 + mask) @ V
// B=4, S=2048, E=1024.
// GEMM: m201 8-phase 256x256, BK=64, 8 waves (2Mx4N), per-wave 128x64.
// Half-tile stream el=4t+7+p staged 7 phases ahead; ONE vmcnt(6) gate per
// K-tile at p3 (tile t+1 fully resident); (row&7)<<4 XOR swizzle (2-way);
// ks-outer MFMA clusters (dep dist 8); setprio; bijective XCD swizzle.
//
// ws layout (MB offsets): 0 qb / 16 kb / 32 vT / 48 Sb(32MB) / 80 xq /
// 96 xk / 112 xv / 128 Wqb / 130 Wkb / 132 Wvb   (total 134MB)

typedef __attribute__((ext_vector_type(8))) short s8v;
typedef __attribute__((ext_vector_type(4))) float f32x4;

__device__ __forceinline__ unsigned short f2b(float f) {
  union { float f; unsigned u; } c; c.f = f;
  unsigned r = c.u + 0x7fffu + ((c.u >> 16) & 1u);
  return (unsigned short)(r >> 16);
}
__device__ __forceinline__ float b2f(unsigned short s) {
  union { float f; unsigned u; } c; c.u = ((unsigned)s) << 16; return c.f;
}

__device__ __forceinline__ void gload_lds16(const void* gsrc, void* ldst) {
  __builtin_amdgcn_global_load_lds(
      (__attribute__((address_space(1))) unsigned int*)(uintptr_t)gsrc,
      (__attribute__((address_space(3))) unsigned int*)(unsigned)(uintptr_t)ldst,
      16, 0, 0);
}

struct Job {
  const unsigned short* A; const unsigned short* B; void* C;
  const float* bias; const float* mask;
  long sAb, sBb, sCb, sMb;
  int lda, ldb, ldc, ldM;
  int K, tilesN, tilesMN;
  float scale; int flags;   // bit0: out bf16; bits1-2: bias 0/1(col)/2(row); bit3: mask
};

// 8-phase 256x256 GEMM, NT: C[m][n] = scale*sum_k A[m][k]B[n][k] (+bias/mask)
__global__ __launch_bounds__(512, 2) void gemm8p(Job j0, Job j1, Job j2,
                                                 int b0, int b1) {
  // A: [buf][256 rows][128B] @0 (64KB); B same @65536. halves: rows 0-127 / 128-255.
  __shared__ __align__(16) char lds[131072];

  const int nwg = gridDim.x;
  int hw = blockIdx.x;
  int g = (hw & 7) * (nwg >> 3) + (hw >> 3);
  const Job J = (g < b0) ? j0 : (g < b1) ? j1 : j2;
  g -= (g < b0) ? 0 : (g < b1) ? b0 : b1;

  const int batch = g / J.tilesMN;
  const int tt = g - batch * J.tilesMN;
  const int tm = tt / J.tilesN, tn = tt - tm * J.tilesN;
  const int brow = tm << 8, bcol = tn << 8;

  const int tid = threadIdx.x, lane = tid & 63, w = tid >> 6;  // 8 waves 2Mx4N
  const int wm = w >> 2, wn = w & 3;
  const int fr = lane & 15, fq = lane >> 4;

  const unsigned short* Ab = J.A + (long)batch * J.sAb;
  const unsigned short* Bb = J.B + (long)batch * J.sBb;
  const int lda = J.lda, ldb = J.ldb;

  // staging: per half-tile (128 rows x 64 cols x 2B = 16KB), each wave does
  // 2 gloads of 1KB (8 rows each). Source col is inverse-swizzled so that
  // swizzled ds_reads see logical data (swizzle: byte4-6 ^= row&7).
  const int srow = (w << 4) + (lane >> 3);
  const int scol = ((lane & 7) ^ ((lane >> 3) & 7)) << 3;
  const unsigned short* pA  = Ab + (long)(brow + srow) * lda + scol;
  const unsigned short* pB  = Bb + (long)(bcol + srow) * ldb + scol;
  const unsigned short* pA1 = pA + 128L * lda;
  const unsigned short* pB1 = pB + 128L * ldb;
  const int dstW = w * 2048;

#define STG_A0(u) { gload_lds16(pA  + (long)(u)*64, lds + ((u)&1)*32768 + dstW); \
                    gload_lds16(pA  + 8L*lda + (long)(u)*64, lds + ((u)&1)*32768 + dstW + 1024); }
#define STG_A1(u) { gload_lds16(pA1 + (long)(u)*64, lds + ((u)&1)*32768 + 16384 + dstW); \
                    gload_lds16(pA1 + 8L*lda + (long)(u)*64, lds + ((u)&1)*32768 + 16384 + dstW + 1024); }
#define STG_B0(u) { gload_lds16(pB  + (long)(u)*64, lds + 65536 + ((u)&1)*32768 + dstW); \
                    gload_lds16(pB  + 8L*ldb + (long)(u)*64, lds + 65536 + ((u)&1)*32768 + dstW + 1024); }
#define STG_B1(u) { gload_lds16(pB1 + (long)(u)*64, lds + 65536 + ((u)&1)*32768 + 16384 + dstW); \
                    gload_lds16(pB1 + 8L*ldb + (long)(u)*64, lds + 65536 + ((u)&1)*32768 + 16384 + dstW + 1024); }

  // ds_read offsets within a 32KB operand buf (swizzled; ^64 toggles ks)
  int offA[8], offB[4];
#pragma unroll
  for (int mi = 0; mi < 8; mi++) {
    const int rA = (mi < 4 ? wm * 64 + mi * 16 : 128 + wm * 64 + (mi - 4) * 16) + fr;
    offA[mi] = rA * 128 + ((fq * 16) ^ ((rA & 7) << 4));
  }
#pragma unroll
  for (int ni = 0; ni < 4; ni++) {
    const int rB = (ni < 2 ? wn * 32 + ni * 16 : 128 + wn * 32 + (ni - 2) * 16) + fr;
    offB[ni] = rB * 128 + ((fq * 16) ^ ((rB & 7) << 4));
  }

  f32x4 acc[8][4];
#pragma unroll
  for (int mi = 0; mi < 8; mi++)
#pragma unroll
    for (int ni = 0; ni < 4; ni++) acc[mi][ni] = (f32x4){0.f, 0.f, 0.f, 0.f};

  const int NT = J.K >> 6;   // >= 2 always (K >= 128)

  // prologue: half-tile stream els 0..6 = tile0{A0,B0,B1,A1} + tile1{A0,B0,B1}
  STG_A0(0); STG_B0(0); STG_B1(0); STG_A1(0);
  STG_A0(1); STG_B0(1); STG_B1(1);
  asm volatile("s_waitcnt vmcnt(6)" ::: "memory");   // tile0 resident
  __builtin_amdgcn_s_barrier();

#define MFMA16(AM, NBASE, BF) \
  __builtin_amdgcn_s_setprio(1); \
  _Pragma("unroll") \
  for (int ks = 0; ks < 2; ks++) \
    _Pragma("unroll") \
    for (int mi = 0; mi < 4; mi++) \
      _Pragma("unroll") \
      for (int ni = 0; ni < 2; ni++) \
        acc[(AM) + mi][(NBASE) + ni] = __builtin_amdgcn_mfma_f32_16x16x32_bf16( \
            a[mi][ks], BF[ni][ks], acc[(AM) + mi][(NBASE) + ni], 0, 0, 0); \
  __builtin_amdgcn_s_setprio(0);

  s8v a[4][2], bb0[2][2], bb1[2][2];
  for (int t = 0; t < NT; ++t) {
    const char* rdA = lds + (t & 1) * 32768;
    const char* rdB = lds + 65536 + (t & 1) * 32768;

    // ---- phase 0: read A-m0 + B-n0; stage A1(t+1); MFMA m0n0
#pragma unroll
    for (int mi = 0; mi < 4; mi++) {
      a[mi][0] = *(const s8v*)(rdA + offA[mi]);
      a[mi][1] = *(const s8v*)(rdA + (offA[mi] ^ 64));
    }
#pragma unroll
    for (int ni = 0; ni < 2; ni++) {
      bb0[ni][0] = *(const s8v*)(rdB + offB[ni]);
      bb0[ni][1] = *(const s8v*)(rdB + (offB[ni] ^ 64));
    }
    if (t + 1 < NT) STG_A1(t + 1);
    __builtin_amdgcn_s_barrier();
    MFMA16(0, 0, bb0);
    __builtin_amdgcn_s_barrier();

    // ---- phase 1: read B-n1; stage A0(t+2); MFMA m0n1
#pragma unroll
    for (int ni = 0; ni < 2; ni++) {
      bb1[ni][0] = *(const s8v*)(rdB + offB[2 + ni]);
      bb1[ni][1] = *(const s8v*)(rdB + (offB[2 + ni] ^ 64));
    }
    if (t + 2 < NT) STG_A0(t + 2);
    __builtin_amdgcn_s_barrier();
    MFMA16(0, 2, bb1);
    __builtin_amdgcn_s_barrier();

    // ---- phase 2: read A-m1; stage B0(t+2); MFMA m1n1
#pragma unroll
    for (int mi = 0; mi < 4; mi++) {
      a[mi][0] = *(const s8v*)(rdA + offA[4 + mi]);
      a[mi][1] = *(const s8v*)(rdA + (offA[4 + mi] ^ 64));
    }
    if (t + 2 < NT) STG_B0(t + 2);
    __builtin_amdgcn_s_barrier();
    MFMA16(4, 2, bb1);
    __builtin_amdgcn_s_barrier();

    // ---- phase 3: stage B1(t+2); MFMA m1n0; gate
    if (t + 2 < NT) STG_B1(t + 2);
    __builtin_amdgcn_s_barrier();
    MFMA16(4, 0, bb0);
    if (t + 2 < NT)      asm volatile("s_waitcnt vmcnt(6)" ::: "memory");
    else if (t + 1 < NT) asm volatile("s_waitcnt vmcnt(0)" ::: "memory");
    __builtin_amdgcn_s_barrier();
  }

  // epilogue: C/D frag layout col=lane&15, row=(lane>>4)*4+r  [m89]
  const int obf = J.flags & 1, bmode = (J.flags >> 1) & 3, hasM = (J.flags >> 3) & 1;
  unsigned short* Cb = (unsigned short*)J.C;
  float* Cf = (float*)J.C;
  const long cB = (long)batch * J.sCb;
  const float* maskB = J.mask + (long)batch * J.sMb;
#pragma unroll
  for (int mi = 0; mi < 8; mi++) {
    const int rloc = (mi < 4 ? wm * 64 + mi * 16 : 128 + wm * 64 + (mi - 4) * 16) + fq * 4;
#pragma unroll
    for (int ni = 0; ni < 4; ni++) {
      const int col = bcol + (ni < 2 ? wn * 32 + ni * 16 : 128 + wn * 32 + (ni - 2) * 16) + fr;
#pragma unroll
      for (int r = 0; r < 4; r++) {
        const int row = brow + rloc + r;
        float v = acc[mi][ni][r] * J.scale;
        if (bmode == 1) v += J.bias[col];
        if (bmode == 2) v += J.bias[row];
        if (hasM) v += maskB[(long)row * J.ldM + col];
        if (obf) Cb[cB + (long)row * J.ldc + col] = f2b(v);
        else     Cf[cB + (long)row * J.ldc + col] = v;
      }
    }
  }
#undef STG_A0
#undef STG_A1
#undef STG_B0
#undef STG_B1
#undef MFMA16
}

// f32->bf16 for 6 regions in one launch. regions 0-2: n8=1048576, 768 blocks
// each; regions 3-5: n8=131072, 128 blocks each. grid = 2688.
__global__ __launch_bounds__(256) void cvt6(
    const float* s0, unsigned short* d0, const float* s1, unsigned short* d1,
    const float* s2, unsigned short* d2, const float* s3, unsigned short* d3,
    const float* s4, unsigned short* d4, const float* s5, unsigned short* d5) {
  int bid = blockIdx.x;
  const float* src; unsigned short* dst; long n8; int lb, nb;
  if (bid < 2304) {
    int r = bid / 768; lb = bid - r * 768; nb = 768; n8 = 1048576;
    src = r == 0 ? s0 : r == 1 ? s1 : s2;
    dst = r == 0 ? d0 : r == 1 ? d1 : d2;
  } else {
    int r = (bid - 2304) / 128; lb = (bid - 2304) - r * 128; nb = 128; n8 = 131072;
    src = r == 0 ? s3 : r == 1 ? s4 : s5;
    dst = r == 0 ? d3 : r == 1 ? d4 : d5;
  }
  const long stride = (long)nb * 256;
  for (long i = (long)lb * 256 + threadIdx.x; i < n8; i += stride) {
    const float* p = src + i * 8;
    f32x4 va = *(const f32x4*)p;
    f32x4 vb = *(const f32x4*)(p + 4);
    s8v o;
    o[0] = (short)f2b(va[0]); o[1] = (short)f2b(va[1]);
    o[2] = (short)f2b(va[2]); o[3] = (short)f2b(va[3]);
    o[4] = (short)f2b(vb[0]); o[5] = (short)f2b(vb[1]);
    o[6] = (short)f2b(vb[2]); o[7] = (short)f2b(vb[3]);
    *(s8v*)(dst + i * 8) = o;
  }
}

// in-place row softmax over 2048 bf16 entries; one block (4 waves) per row
__global__ __launch_bounds__(256) void softmax_inplace(unsigned short* __restrict__ S) {
  const long row = blockIdx.x;
  unsigned short* rp = S + row * 2048;
  const int tid = threadIdx.x, lane = tid & 63, wid = tid >> 6;

  s8v vb = *(const s8v*)&rp[tid * 8];
  float x[8];
#pragma unroll
  for (int j = 0; j < 8; j++) x[j] = b2f((unsigned short)vb[j]);

  float m = x[0];
#pragma unroll
  for (int j = 1; j < 8; j++) m = fmaxf(m, x[j]);
#pragma unroll
  for (int off = 32; off > 0; off >>= 1) m = fmaxf(m, __shfl_xor(m, off, 64));

  __shared__ float red[4];
  if (lane == 0) red[wid] = m;
  __syncthreads();
  m = fmaxf(fmaxf(red[0], red[1]), fmaxf(red[2], red[3]));
  __syncthreads();

  float s = 0.f;
#pragma unroll
  for (int j = 0; j < 8; j++) { x[j] = __expf(x[j] - m); s += x[j]; }
#pragma unroll
  for (int off = 32; off > 0; off >>= 1) s += __shfl_xor(s, off, 64);
  if (lane == 0) red[wid] = s;
  __syncthreads();
  s = red[0] + red[1] + red[2] + red[3];
  const float inv = 1.0f / s;

  s8v ob;
#pragma unroll
  for (int j = 0; j < 8; j++) ob[j] = (short)f2b(x[j] * inv);
  *(s8v*)&rp[tid * 8] = ob;
}

extern "C" void kernel_launch(void* const* d_in, const int* in_sizes, int n_in,
                              void* d_out, int out_size, void* d_ws, size_t ws_size,
                              hipStream_t stream) {
  const float* q    = (const float*)d_in[0];
  const float* k    = (const float*)d_in[1];
  const float* v    = (const float*)d_in[2];
  const float* mask = (const float*)d_in[3];
  const float* Wq   = (const float*)d_in[4];
  const float* bq   = (const float*)d_in[5];
  const float* Wk   = (const float*)d_in[6];
  const float* bk   = (const float*)d_in[7];
  const float* Wv   = (const float*)d_in[8];
  const float* bv   = (const float*)d_in[9];
  float* out = (float*)d_out;

  const size_t MB = 1ull << 20;
  if (ws_size < 134 * MB) return;
  char* ws = (char*)d_ws;
  unsigned short* qb  = (unsigned short*)(ws + 0 * MB);
  unsigned short* kb  = (unsigned short*)(ws + 16 * MB);
  unsigned short* vT  = (unsigned short*)(ws + 32 * MB);
  unsigned short* Sb  = (unsigned short*)(ws + 48 * MB);
  unsigned short* xq  = (unsigned short*)(ws + 80 * MB);
  unsigned short* xk  = (unsigned short*)(ws + 96 * MB);
  unsigned short* xv  = (unsigned short*)(ws + 112 * MB);
  unsigned short* Wqb = (unsigned short*)(ws + 128 * MB);
  unsigned short* Wkb = (unsigned short*)(ws + 130 * MB);
  unsigned short* Wvb = (unsigned short*)(ws + 132 * MB);

  cvt6<<<2688, 256, 0, stream>>>(q, xq, k, xk, v, xv, Wq, Wqb, Wk, Wkb, Wv, Wvb);

  // q,k projections: M=8192 N=1024 (32x4=128 tiles each); v transposed:
  // vT[f][s], M=1024 N=2048 per batch (4x8x4=128 tiles). 384 blocks total.
  Job jq = { xq, Wqb, (void*)qb, bq, nullptr, 0, 0, 0, 0,
             1024, 1024, 1024, 0, 1024, 4, 128, 1.0f, 1 | (1 << 1) };
  Job jk = { xk, Wkb, (void*)kb, bk, nullptr, 0, 0, 0, 0,
             1024, 1024, 1024, 0, 1024, 4, 128, 1.0f, 1 | (1 << 1) };
  Job jv = { Wvb, xv, (void*)vT, bv, nullptr, 0, 2048L * 1024, 1024L * 2048, 0,
             1024, 1024, 2048, 0, 1024, 8, 32, 1.0f, 1 | (2 << 1) };
  gemm8p<<<384, 512, 0, stream>>>(jq, jk, jv, 128, 256);

  // scores: S = (qb.kb^T)/32 + mask; M=N=2048, K=1024, 8x8x4=256 blocks
  Job js = { qb, kb, (void*)Sb, nullptr, mask,
             2048L * 1024, 2048L * 1024, 2048L * 2048, 2048L * 2048,
             1024, 1024, 2048, 2048, 1024, 8, 64, 0.03125f, 1 | (1 << 3) };
  gemm8p<<<256, 512, 0, stream>>>(js, js, js, 256, 256);

  softmax_inplace<<<8192, 256, 0, stream>>>(Sb);

  // PV: out = P.vT^T; M=2048 N=1024, K=2048, 8x4x4=128 blocks
  Job jp = { Sb, vT, (void*)out, nullptr, nullptr,
             2048L * 2048, 1024L * 2048, 2048L * 1024, 0,
             2048, 2048, 1024, 0, 2048, 4, 32, 1.0f, 0 };
  gemm8p<<<128, 512, 0, stream>>>(jp, jp, jp, 128, 128);
}

// Round 5
// 289.308 us; speedup vs baseline: 1.1353x; 1.0894x over previous
//
#include <hip/hip_runtime.h>
#include <stdint.h>

// Fused attention: q/k/v projections + softmax(QK^T/32 + mask) @ V
// B=4, S=2048, E=1024.
// GEMM: occupancy-first counted-vmcnt ring. 128x128 tile, BK=32, 4 waves
// (2x2 of 64x64), ring-3 LDS (48KB -> 3 blocks/CU), stage 2 tiles ahead via
// global_load_lds(16B), ONE barrier + vmcnt(4) gate per K-tile, R2-verified
// XOR swizzle (0 conflicts), bijective XCD swizzle, multi-job fused launches.
//
// ws layout (MB offsets): 0 qb / 16 kb / 32 vT / 48 Sb(32MB) / 80 xq /
// 96 xk / 112 xv / 128 Wqb / 130 Wkb / 132 Wvb   (total 134MB)

typedef __attribute__((ext_vector_type(8))) short s8v;
typedef __attribute__((ext_vector_type(4))) float f32x4;

__device__ __forceinline__ unsigned short f2b(float f) {
  union { float f; unsigned u; } c; c.f = f;
  unsigned r = c.u + 0x7fffu + ((c.u >> 16) & 1u);
  return (unsigned short)(r >> 16);
}
__device__ __forceinline__ float b2f(unsigned short s) {
  union { float f; unsigned u; } c; c.u = ((unsigned)s) << 16; return c.f;
}

__device__ __forceinline__ void gload_lds16(const void* gsrc, void* ldst) {
  __builtin_amdgcn_global_load_lds(
      (__attribute__((address_space(1))) unsigned int*)(uintptr_t)gsrc,
      (__attribute__((address_space(3))) unsigned int*)(unsigned)(uintptr_t)ldst,
      16, 0, 0);
}

struct Job {
  const unsigned short* A; const unsigned short* B; void* C;
  const float* bias; const float* mask;
  long sAb, sBb, sCb, sMb;
  int lda, ldb, ldc, ldM;
  int K, tilesN, tilesMN;
  float scale; int flags;   // bit0: out bf16; bits1-2: bias 0/1(col)/2(row); bit3: mask
};

// NT GEMM: C[m][n] = scale*sum_k A[m][k]B[n][k] (+bias/mask). Tiles 128x128.
__global__ __launch_bounds__(256, 3) void gemm_r3(Job j0, Job j1, Job j2,
                                                  int b0, int b1) {
  constexpr int SLOT = 16384;            // 8KB A (128x32 bf16) + 8KB B
  __shared__ __align__(16) char lds[3 * SLOT];

  const int nwg = gridDim.x;
  const int hw = blockIdx.x;
  int g = (hw & 7) * (nwg >> 3) + (hw >> 3);   // bijective XCD swizzle (nwg%8==0)
  const Job J = (g < b0) ? j0 : (g < b1) ? j1 : j2;
  g -= (g < b0) ? 0 : (g < b1) ? b0 : b1;

  const int batch = g / J.tilesMN;
  const int tt = g - batch * J.tilesMN;
  const int tm = tt / J.tilesN, tn = tt - tm * J.tilesN;
  const int brow = tm << 7, bcol = tn << 7;

  const int tid = threadIdx.x, lane = tid & 63, w = tid >> 6;  // 4 waves 2x2
  const int wr = w >> 1, wc = w & 1;
  const int fr = lane & 15, fq = lane >> 4;

  const unsigned short* Ab = J.A + (long)batch * J.sAb;
  const unsigned short* Bb = J.B + (long)batch * J.sBb;
  const int lda = J.lda, ldb = J.ldb;

  // staging: 16 chunks of 1KB (A: 0-7, B: 8-15), wave w stages {w, w+4, w+8,
  // w+12}. LDS dest linear (wave-uniform base + lane*16); global source is
  // inverse-swizzled so swizzled ds_reads see logical data (rule #21).
  const unsigned short* gsrc[4];
  int ldsdst[4];
#pragma unroll
  for (int i = 0; i < 4; i++) {
    const int c = w + i * 4;
    const bool isA = (c < 8);
    const int cc = isA ? c : c - 8;
    const int roff = cc * 1024 + lane * 16;          // region-relative linear
    const int L = roff ^ (((roff >> 7) & 7) << 4);   // involution (R2-verified)
    const int row = L >> 6, colb = L & 63;
    gsrc[i] = (isA ? (Ab + (long)(brow + row) * lda)
                   : (Bb + (long)(bcol + row) * ldb)) + (colb >> 1);
    ldsdst[i] = (isA ? 0 : 8192) + cc * 1024;
  }

  // ds_read offsets (region-relative, swizzled with the SAME involution)
  int offA[4], offB[4];
#pragma unroll
  for (int i = 0; i < 4; i++) {
    const int oa = (wr * 64 + i * 16 + fr) * 64 + fq * 16;
    offA[i] = oa ^ (((oa >> 7) & 7) << 4);
    const int ob = (wc * 64 + i * 16 + fr) * 64 + fq * 16;
    offB[i] = 8192 + (ob ^ (((ob >> 7) & 7) << 4));
  }

  f32x4 acc[4][4];
#pragma unroll
  for (int mi = 0; mi < 4; mi++)
#pragma unroll
    for (int ni = 0; ni < 4; ni++) acc[mi][ni] = (f32x4){0.f, 0.f, 0.f, 0.f};

  const int NT = J.K >> 5;   // K multiple of 32; K>=1024 here

#define STAGE(kt, slot) { \
  char* const sb_ = lds + (slot) * SLOT; \
  _Pragma("unroll") \
  for (int i_ = 0; i_ < 4; i_++) \
    gload_lds16(gsrc[i_] + (long)(kt) * 32, sb_ + ldsdst[i_]); }

  // prologue: stage tiles 0,1 into slots 0,1; tile 0 resident block-wide
  STAGE(0, 0);
  STAGE(1, 1);
  asm volatile("s_waitcnt vmcnt(4)" ::: "memory");
  __builtin_amdgcn_s_barrier();

  int sRead = 0, sStage = 2;
  for (int t = 0; t < NT; ++t) {
    if (t + 2 < NT) STAGE(t + 2, sStage);   // slot != sRead, != (t+1)'s slot
    const char* sb = lds + sRead * SLOT;

    s8v af[4], bf[4];
#pragma unroll
    for (int mi = 0; mi < 4; mi++) af[mi] = *(const s8v*)(sb + offA[mi]);
#pragma unroll
    for (int ni = 0; ni < 4; ni++) bf[ni] = *(const s8v*)(sb + offB[ni]);
#pragma unroll
    for (int mi = 0; mi < 4; mi++)
#pragma unroll
      for (int ni = 0; ni < 4; ni++)
        acc[mi][ni] = __builtin_amdgcn_mfma_f32_16x16x32_bf16(
            af[mi], bf[ni], acc[mi][ni], 0, 0, 0);

    if (t + 1 < NT) {
      if (t + 2 < NT) asm volatile("s_waitcnt vmcnt(4)" ::: "memory");
      else            asm volatile("s_waitcnt vmcnt(0)" ::: "memory");
      __builtin_amdgcn_s_barrier();
    }
    sRead  = (sRead  == 2) ? 0 : sRead  + 1;
    sStage = (sStage == 2) ? 0 : sStage + 1;
  }

  // epilogue: C/D frag layout col=lane&15, row=(lane>>4)*4+r  [m89]
  const int obf = J.flags & 1, bmode = (J.flags >> 1) & 3, hasM = (J.flags >> 3) & 1;
  unsigned short* Cb = (unsigned short*)J.C;
  float* Cf = (float*)J.C;
  const long cB = (long)batch * J.sCb;
  const float* maskB = J.mask + (long)batch * J.sMb;
#pragma unroll
  for (int mi = 0; mi < 4; mi++) {
#pragma unroll
    for (int ni = 0; ni < 4; ni++) {
      const int col = bcol + wc * 64 + ni * 16 + fr;
#pragma unroll
      for (int r = 0; r < 4; r++) {
        const int row = brow + wr * 64 + mi * 16 + fq * 4 + r;
        float v = acc[mi][ni][r] * J.scale;
        if (bmode == 1) v += J.bias[col];
        if (bmode == 2) v += J.bias[row];
        if (hasM) v += maskB[(long)row * J.ldM + col];
        if (obf) Cb[cB + (long)row * J.ldc + col] = f2b(v);
        else     Cf[cB + (long)row * J.ldc + col] = v;
      }
    }
  }
#undef STAGE
}

// f32->bf16 for 6 regions in one launch. regions 0-2: n8=1048576, 768 blocks
// each; regions 3-5: n8=131072, 128 blocks each. grid = 2688.
__global__ __launch_bounds__(256) void cvt6(
    const float* s0, unsigned short* d0, const float* s1, unsigned short* d1,
    const float* s2, unsigned short* d2, const float* s3, unsigned short* d3,
    const float* s4, unsigned short* d4, const float* s5, unsigned short* d5) {
  int bid = blockIdx.x;
  const float* src; unsigned short* dst; long n8; int lb, nb;
  if (bid < 2304) {
    int r = bid / 768; lb = bid - r * 768; nb = 768; n8 = 1048576;
    src = r == 0 ? s0 : r == 1 ? s1 : s2;
    dst = r == 0 ? d0 : r == 1 ? d1 : d2;
  } else {
    int r = (bid - 2304) / 128; lb = (bid - 2304) - r * 128; nb = 128; n8 = 131072;
    src = r == 0 ? s3 : r == 1 ? s4 : s5;
    dst = r == 0 ? d3 : r == 1 ? d4 : d5;
  }
  const long stride = (long)nb * 256;
  for (long i = (long)lb * 256 + threadIdx.x; i < n8; i += stride) {
    const float* p = src + i * 8;
    f32x4 va = *(const f32x4*)p;
    f32x4 vb = *(const f32x4*)(p + 4);
    s8v o;
    o[0] = (short)f2b(va[0]); o[1] = (short)f2b(va[1]);
    o[2] = (short)f2b(va[2]); o[3] = (short)f2b(va[3]);
    o[4] = (short)f2b(vb[0]); o[5] = (short)f2b(vb[1]);
    o[6] = (short)f2b(vb[2]); o[7] = (short)f2b(vb[3]);
    *(s8v*)(dst + i * 8) = o;
  }
}

// in-place row softmax over 2048 bf16 entries; one block (4 waves) per row
__global__ __launch_bounds__(256) void softmax_inplace(unsigned short* __restrict__ S) {
  const long row = blockIdx.x;
  unsigned short* rp = S + row * 2048;
  const int tid = threadIdx.x, lane = tid & 63, wid = tid >> 6;

  s8v vb = *(const s8v*)&rp[tid * 8];
  float x[8];
#pragma unroll
  for (int j = 0; j < 8; j++) x[j] = b2f((unsigned short)vb[j]);

  float m = x[0];
#pragma unroll
  for (int j = 1; j < 8; j++) m = fmaxf(m, x[j]);
#pragma unroll
  for (int off = 32; off > 0; off >>= 1) m = fmaxf(m, __shfl_xor(m, off, 64));

  __shared__ float red[4];
  if (lane == 0) red[wid] = m;
  __syncthreads();
  m = fmaxf(fmaxf(red[0], red[1]), fmaxf(red[2], red[3]));
  __syncthreads();

  float s = 0.f;
#pragma unroll
  for (int j = 0; j < 8; j++) { x[j] = __expf(x[j] - m); s += x[j]; }
#pragma unroll
  for (int off = 32; off > 0; off >>= 1) s += __shfl_xor(s, off, 64);
  if (lane == 0) red[wid] = s;
  __syncthreads();
  s = red[0] + red[1] + red[2] + red[3];
  const float inv = 1.0f / s;

  s8v ob;
#pragma unroll
  for (int j = 0; j < 8; j++) ob[j] = (short)f2b(x[j] * inv);
  *(s8v*)&rp[tid * 8] = ob;
}

extern "C" void kernel_launch(void* const* d_in, const int* in_sizes, int n_in,
                              void* d_out, int out_size, void* d_ws, size_t ws_size,
                              hipStream_t stream) {
  const float* q    = (const float*)d_in[0];
  const float* k    = (const float*)d_in[1];
  const float* v    = (const float*)d_in[2];
  const float* mask = (const float*)d_in[3];
  const float* Wq   = (const float*)d_in[4];
  const float* bq   = (const float*)d_in[5];
  const float* Wk   = (const float*)d_in[6];
  const float* bk   = (const float*)d_in[7];
  const float* Wv   = (const float*)d_in[8];
  const float* bv   = (const float*)d_in[9];
  float* out = (float*)d_out;

  const size_t MB = 1ull << 20;
  if (ws_size < 134 * MB) return;
  char* ws = (char*)d_ws;
  unsigned short* qb  = (unsigned short*)(ws + 0 * MB);
  unsigned short* kb  = (unsigned short*)(ws + 16 * MB);
  unsigned short* vT  = (unsigned short*)(ws + 32 * MB);
  unsigned short* Sb  = (unsigned short*)(ws + 48 * MB);
  unsigned short* xq  = (unsigned short*)(ws + 80 * MB);
  unsigned short* xk  = (unsigned short*)(ws + 96 * MB);
  unsigned short* xv  = (unsigned short*)(ws + 112 * MB);
  unsigned short* Wqb = (unsigned short*)(ws + 128 * MB);
  unsigned short* Wkb = (unsigned short*)(ws + 130 * MB);
  unsigned short* Wvb = (unsigned short*)(ws + 132 * MB);

  cvt6<<<2688, 256, 0, stream>>>(q, xq, k, xk, v, xv, Wq, Wqb, Wk, Wkb, Wv, Wvb);

  // QKV fused: q-proj 512 blocks (64x8 tiles), k-proj 512, v-proj 512
  // (vT[f][s]: A=Wvb M=1024 -> 8x16 tiles x 4 batches). grid 1536 = 6/CU.
  Job jq = { xq, Wqb, (void*)qb, bq, nullptr, 0, 0, 0, 0,
             1024, 1024, 1024, 0, 1024, 8, 512, 1.0f, 1 | (1 << 1) };
  Job jk = { xk, Wkb, (void*)kb, bk, nullptr, 0, 0, 0, 0,
             1024, 1024, 1024, 0, 1024, 8, 512, 1.0f, 1 | (1 << 1) };
  Job jv = { Wvb, xv, (void*)vT, bv, nullptr, 0, 2048L * 1024, 1024L * 2048, 0,
             1024, 1024, 2048, 0, 1024, 16, 128, 1.0f, 1 | (2 << 1) };
  gemm_r3<<<1536, 256, 0, stream>>>(jq, jk, jv, 512, 1024);

  // scores: S = (qb.kb^T)/32 + mask; 16x16 tiles x 4 batches = 1024 blocks
  Job js = { qb, kb, (void*)Sb, nullptr, mask,
             2048L * 1024, 2048L * 1024, 2048L * 2048, 2048L * 2048,
             1024, 1024, 2048, 2048, 1024, 16, 256, 0.03125f, 1 | (1 << 3) };
  gemm_r3<<<1024, 256, 0, stream>>>(js, js, js, 1024, 1024);

  softmax_inplace<<<8192, 256, 0, stream>>>(Sb);

  // PV: out = P.vT^T; 16x8 tiles x 4 batches = 512 blocks, K=2048
  Job jp = { Sb, vT, (void*)out, nullptr, nullptr,
             2048L * 2048, 1024L * 2048, 2048L * 1024, 0,
             2048, 2048, 1024, 0, 2048, 8, 128, 1.0f, 0 };
  gemm_r3<<<512, 256, 0, stream>>>(jp, jp, jp, 512, 512);
}